// Round 7
// baseline (47.462 us; speedup 1.0000x reference)
//
#include <hip/hip_runtime.h>
#include <hip/hip_bf16.h>

typedef __attribute__((ext_vector_type(8))) short short8;
typedef __attribute__((ext_vector_type(4))) float f32x4;
typedef __attribute__((ext_vector_type(2))) float f32x2;
typedef __attribute__((ext_vector_type(4))) unsigned int u32x4;

#define NROWS   262144
#define ODIM    64
#define NBLOCKS 512
#define TPB     512           // 8 waves; 98 KB LDS -> 1 block/CU -> 2 waves/SIMD (reg cap 256)
#define INV2PI  0.15915494309189535f

__device__ __forceinline__ float cos2pi(float f){ float r; asm("v_cos_f32 %0, %1" : "=v"(r) : "v"(f)); return r; }
__device__ __forceinline__ float sin2pi(float f){ float r; asm("v_sin_f32 %0, %1" : "=v"(r) : "v"(f)); return r; }
// packed dual-fp32 ops (VOP3P)
__device__ __forceinline__ f32x2 pk_mul(f32x2 a, f32x2 b){
    f32x2 d; asm("v_pk_mul_f32 %0, %1, %2" : "=v"(d) : "v"(a), "v"(b)); return d; }
__device__ __forceinline__ f32x2 pk_fma(f32x2 a, f32x2 b, f32x2 c){
    f32x2 d; asm("v_pk_fma_f32 %0, %1, %2, %3" : "=v"(d) : "v"(a), "v"(b), "v"(c)); return d; }
__device__ __forceinline__ f32x2 pk_fms(f32x2 a, f32x2 b, f32x2 c){   // a*b - c
    f32x2 d; asm("v_pk_fma_f32 %0, %1, %2, %3 neg_lo:[0,0,1] neg_hi:[0,0,1]"
                 : "=v"(d) : "v"(a), "v"(b), "v"(c)); return d; }
// D.lo = bf16(lo), D.hi = bf16(hi), RNE
__device__ __forceinline__ unsigned pkbf(float lo, float hi){
    unsigned r; asm("v_cvt_pk_bf16_f32 %0, %1, %2" : "=v"(r) : "v"(lo), "v"(hi)); return r; }
__device__ __forceinline__ short8 as_s8(u32x4 v){ union{u32x4 u; short8 s;} x; x.u = v; return x.s; }
__device__ __forceinline__ short bf16_of(float f){
    union { __hip_bfloat16 h; short s; } u; u.h = __float2bfloat16(f); return u.s; }

// out[b,o] = sum_k F[b,k] W[o,k]; k = br*384 + i*128 + g; harmonic = g+1
// cos k-step kk (0..11) pairs with sin k-step kk+12 (identical harmonics).
extern "C" __global__ void __launch_bounds__(TPB, 2)
fourier_mfma(const float* __restrict__ x,
             const float* __restrict__ coeffs,
             const float* __restrict__ bias,
             float* __restrict__ out)
{
    // Fragment-ordered bf16 weights: [ks][nt][lane] -> 8 bf16 (one ds_read_b128)
    __shared__ short8 Wlds[24 * 4 * 64];   // 98304 B

    const int tid = threadIdx.x;

    // ---- one-time weight staging: fp32 global -> bf16 fragments in LDS ----
    for (int fl = tid; fl < 24*4*64; fl += TPB) {
        const int ks = fl >> 8;
        const int nt = (fl >> 6) & 3;
        const int ln = fl & 63;
        const int o  = nt*16 + (ln & 15);   // B-frag: col = lane & 15
        const int kg = ln >> 4;             // k sub-band = 4*(lane>>4)
        union { short8 v; short s[8]; } fr;
        #pragma unroll
        for (int h = 0; h < 2; ++h) {
            const int kb  = ks*32 + h*16;
            const int br  = (kb >= 384) ? 1 : 0;
            const int rem = kb - br*384;
            const int ii  = rem >> 7;
            const int g0  = (rem & 127) + kg*4;
            const float* wp = coeffs + (((br*ODIM + o)*3 + ii) << 7) + g0;
            #pragma unroll
            for (int j = 0; j < 4; ++j) fr.s[h*4 + j] = bf16_of(wp[j]);
        }
        Wlds[fl] = fr.v;
    }

    const int lane = tid & 63;
    const int wid  = tid >> 6;
    const int mrow = lane & 15;     // A-frag row within 16-row tile
    const int kgrp = lane >> 4;     // k sub-band / D-row group
    const float h0f = (float)(4*kgrp + 1);   // lane's anchor harmonic per 16-block

    const int unit = blockIdx.x * 8 + wid;   // 512*8 = 4096 units = NROWS/64, exact
    const int base = unit * 64;

    // x (revolutions) for 4 row-tiles as 2 packed pairs: pair p = tiles {2p, 2p+1}
    f32x2 xr[2][3];
    #pragma unroll
    for (int p = 0; p < 2; ++p) {
        const int rowA = base + (2*p + 0)*16 + mrow;
        const int rowB = base + (2*p + 1)*16 + mrow;
        #pragma unroll
        for (int i = 0; i < 3; ++i)
            xr[p][i] = (f32x2){ x[rowA*3 + i] * INV2PI, x[rowB*3 + i] * INV2PI };
    }
    float bcol[4];
    #pragma unroll
    for (int nt = 0; nt < 4; ++nt) bcol[nt] = bias[nt*16 + mrow];

    __syncthreads();

// Per-input-dim trig anchors for pair P (12 transcendentals per 4 k-steps)
#define ANCHOR(P, I) do {                                           \
    const f32x2 a = xr[P][I];                                       \
    cv[P]  = (f32x2){ cos2pi(a.x), cos2pi(a.y) };                   \
    sv[P]  = (f32x2){ sin2pi(a.x), sin2pi(a.y) };                   \
    f32x2 t = (f32x2){ 16.f*a.x, 16.f*a.y };                        \
    t.x -= floorf(t.x); t.y -= floorf(t.y);                         \
    c16[P] = (f32x2){ cos2pi(t.x), cos2pi(t.y) };                   \
    s16[P] = (f32x2){ sin2pi(t.x), sin2pi(t.y) };                   \
    f32x2 u = (f32x2){ h0f*a.x, h0f*a.y };                          \
    u.x -= floorf(u.x); u.y -= floorf(u.y);                         \
    stc[P] = (f32x2){ cos2pi(u.x), cos2pi(u.y) };                   \
    sts[P] = (f32x2){ sin2pi(u.x), sin2pi(u.y) };                   \
} while (0)

// One 16-k half-block for pair P: 4 chain values, packed dual-FMA rotations
#define HALF(P, D0, D1) do {                                        \
    const f32x2 c0 = stc[P], s0 = sts[P];                           \
    const f32x2 c1 = pk_fms(c0, cv[P], pk_mul(s0, sv[P]));          \
    const f32x2 s1 = pk_fma(s0, cv[P], pk_mul(c0, sv[P]));          \
    fCA[P].D0 = pkbf(c0.x, c1.x);  fCB[P].D0 = pkbf(c0.y, c1.y);    \
    fSA[P].D0 = pkbf(s0.x, s1.x);  fSB[P].D0 = pkbf(s0.y, s1.y);    \
    const f32x2 c2 = pk_fms(c1, cv[P], pk_mul(s1, sv[P]));          \
    const f32x2 s2 = pk_fma(s1, cv[P], pk_mul(c1, sv[P]));          \
    const f32x2 c3 = pk_fms(c2, cv[P], pk_mul(s2, sv[P]));          \
    const f32x2 s3 = pk_fma(s2, cv[P], pk_mul(c2, sv[P]));          \
    fCA[P].D1 = pkbf(c2.x, c3.x);  fCB[P].D1 = pkbf(c2.y, c3.y);    \
    fSA[P].D1 = pkbf(s2.x, s3.x);  fSB[P].D1 = pkbf(s2.y, s3.y);    \
    const f32x2 nc = pk_fms(stc[P], c16[P], pk_mul(sts[P], s16[P]));\
    const f32x2 ns = pk_fma(stc[P], s16[P], pk_mul(sts[P], c16[P]));\
    stc[P] = nc; sts[P] = ns;                                       \
} while (0)

    f32x4 acc[4][4];   // [row-tile][nt]
    #pragma unroll
    for (int rt = 0; rt < 4; ++rt)
        #pragma unroll
        for (int nt = 0; nt < 4; ++nt)
            acc[rt][nt] = (f32x4){0.f, 0.f, 0.f, 0.f};

    f32x2 cv[2], sv[2], c16[2], s16[2], stc[2], sts[2];
    short8 bc[2][4], bs[2][4];     // double-buffered b-frags (static idx after unroll)

    #pragma unroll
    for (int nt = 0; nt < 4; ++nt) {
        bc[0][nt] = Wlds[(0*4 + nt)*64 + lane];
        bs[0][nt] = Wlds[(12*4 + nt)*64 + lane];
    }

    #pragma unroll
    for (int kk = 0; kk < 12; ++kk) {
        const int cur = kk & 1;
        // prefetch next step's b-frags; latency hidden under FEAT + MFMAs below
        if (kk < 11) {
            #pragma unroll
            for (int nt = 0; nt < 4; ++nt) {
                bc[cur^1][nt] = Wlds[((kk+1)*4 + nt)*64 + lane];
                bs[cur^1][nt] = Wlds[((kk+13)*4 + nt)*64 + lane];
            }
        }

        if ((kk & 3) == 0) { ANCHOR(0, kk >> 2); ANCHOR(1, kk >> 2); }

        u32x4 fCA[2], fCB[2], fSA[2], fSB[2];
        HALF(0, x, y);  HALF(0, z, w);
        HALF(1, x, y);  HALF(1, z, w);

        // 32 MFMAs grouped by A-frag: same-acc reuse distance = 16
        __builtin_amdgcn_s_setprio(1);
        #pragma unroll
        for (int p = 0; p < 2; ++p) {
            const short8 fA = as_s8(fCA[p]);
            const short8 fB = as_s8(fCB[p]);
            #pragma unroll
            for (int nt = 0; nt < 4; ++nt)
                acc[2*p+0][nt] = __builtin_amdgcn_mfma_f32_16x16x32_bf16(fA, bc[cur][nt], acc[2*p+0][nt], 0, 0, 0);
            #pragma unroll
            for (int nt = 0; nt < 4; ++nt)
                acc[2*p+1][nt] = __builtin_amdgcn_mfma_f32_16x16x32_bf16(fB, bc[cur][nt], acc[2*p+1][nt], 0, 0, 0);
        }
        #pragma unroll
        for (int p = 0; p < 2; ++p) {
            const short8 fA = as_s8(fSA[p]);
            const short8 fB = as_s8(fSB[p]);
            #pragma unroll
            for (int nt = 0; nt < 4; ++nt)
                acc[2*p+0][nt] = __builtin_amdgcn_mfma_f32_16x16x32_bf16(fA, bs[cur][nt], acc[2*p+0][nt], 0, 0, 0);
            #pragma unroll
            for (int nt = 0; nt < 4; ++nt)
                acc[2*p+1][nt] = __builtin_amdgcn_mfma_f32_16x16x32_bf16(fB, bs[cur][nt], acc[2*p+1][nt], 0, 0, 0);
        }
        __builtin_amdgcn_s_setprio(0);
    }

    // Epilogue. D layout: col = lane&15, row = 4*(lane>>4) + reg  [m89-verified]
    #pragma unroll
    for (int rt = 0; rt < 4; ++rt) {
        const int row0 = base + rt*16 + kgrp*4;
        #pragma unroll
        for (int nt = 0; nt < 4; ++nt) {
            #pragma unroll
            for (int q = 0; q < 4; ++q) {
                out[(row0 + q)*ODIM + nt*16 + mrow] = acc[rt][nt][q] + bcol[nt];
            }
        }
    }
#undef HALF
#undef ANCHOR
}

extern "C" void kernel_launch(void* const* d_in, const int* in_sizes, int n_in,
                              void* d_out, int out_size, void* d_ws, size_t ws_size,
                              hipStream_t stream) {
    const float* x      = (const float*)d_in[0];
    const float* coeffs = (const float*)d_in[1];
    const float* bias   = (const float*)d_in[2];
    float* out = (float*)d_out;
    (void)in_sizes; (void)n_in; (void)out_size; (void)d_ws; (void)ws_size;
    hipLaunchKernelGGL(fourier_mfma, dim3(NBLOCKS), dim3(TPB), 0, stream, x, coeffs, bias, out);
}